// Round 16
// baseline (192.198 us; speedup 1.0000x reference)
//
#include <hip/hip_runtime.h>
#include <hip/hip_bf16.h>

#define D_MODEL 96
#define D_INNER 192
#define BATCH 32
#define HH 56
#define WW 56
#define NPIX (BATCH*HH*WW)   // 100352
#define LN_EPS 1e-5f
#define TAPS 18432           // shorts per tap slab (96 oc * 192 ic)
#define TAPBYTES 36864
#define K2_NWG 784           // NPIX / 128 = 8 * 98 (bijective XCD swizzle)
#define K2_CPX 98

typedef unsigned short ushort_t;
typedef __attribute__((ext_vector_type(8))) short short8;   // 8 bf16 (4 VGPRs)
typedef __attribute__((ext_vector_type(4))) float f32x4;

__device__ __align__(16) ushort_t g_Wt[9 * 96 * 192];
__device__ __align__(16) ushort_t g_Wit[192 * 96];

static __device__ __forceinline__ unsigned short f2bf(float f) {
    unsigned u = __float_as_uint(f);
    unsigned r = (u + 0x7fffu + ((u >> 16) & 1u)) >> 16;
    return (unsigned short)r;
}

// ---------------------------------------------------------------------------
// Kernel 0: weight prep. (unchanged, verified)
// ---------------------------------------------------------------------------
__global__ __launch_bounds__(256) void k0_wt(const float* __restrict__ Wc,
                                             const float* __restrict__ Wi) {
    const int o = blockIdx.x * 256 + threadIdx.x;
    if (o < 9 * 96 * 192) {
        const int tap = o / (96 * 192);
        const int rem = o - tap * 96 * 192;
        const int oc = rem / 192;
        const int ic = rem - oc * 192;
        g_Wt[o] = f2bf(Wc[(tap * 192 + ic) * 96 + oc]);
    }
    if (o < 192 * 96) {
        const int oc = o / 96, ic = o - oc * 96;
        g_Wit[o] = f2bf(Wi[ic * 384 + oc]);
    }
}

// ---------------------------------------------------------------------------
// Kernel 1: LayerNorm + in_projection. (byte-identical to round 9/11/15)
// ---------------------------------------------------------------------------
__global__ __launch_bounds__(256) void k1_ln_proj(
    const float* __restrict__ X, const float* __restrict__ ln_w,
    const float* __restrict__ ln_b, const float* __restrict__ b_in,
    ushort_t* __restrict__ X1)
{
    __shared__ ushort_t sH[64 * 104];
    __shared__ ushort_t sO[64 * 200];
    const int t = threadIdx.x;

    const int g = t >> 2, tig = t & 3;
    const int pix = blockIdx.x * 64 + g;
    const float* xp = X + (size_t)pix * 96 + tig * 24;
    float4 xq[6];
    float s = 0.f;
    #pragma unroll
    for (int c = 0; c < 6; ++c) {
        xq[c] = *(const float4*)(xp + c * 4);
        s += xq[c].x + xq[c].y + xq[c].z + xq[c].w;
    }
    s += __shfl_xor(s, 1, 4);
    s += __shfl_xor(s, 2, 4);
    const float mu = s * (1.f / 96.f);
    float v = 0.f;
    #pragma unroll
    for (int c = 0; c < 6; ++c) {
        const float d0 = xq[c].x - mu, d1 = xq[c].y - mu;
        const float d2 = xq[c].z - mu, d3 = xq[c].w - mu;
        v += d0 * d0 + d1 * d1 + d2 * d2 + d3 * d3;
    }
    v += __shfl_xor(v, 1, 4);
    v += __shfl_xor(v, 2, 4);
    const float rs = rsqrtf(v * (1.f / 96.f) + LN_EPS);
    #pragma unroll
    for (int c = 0; c < 6; ++c) {
        const float4 lw = *(const float4*)(ln_w + tig * 24 + c * 4);
        const float4 lb = *(const float4*)(ln_b + tig * 24 + c * 4);
        const unsigned p0 = (unsigned)f2bf((xq[c].x - mu) * rs * lw.x + lb.x)
                          | ((unsigned)f2bf((xq[c].y - mu) * rs * lw.y + lb.y) << 16);
        const unsigned p1 = (unsigned)f2bf((xq[c].z - mu) * rs * lw.z + lb.z)
                          | ((unsigned)f2bf((xq[c].w - mu) * rs * lw.w + lb.w) << 16);
        uint2 u; u.x = p0; u.y = p1;
        *(uint2*)&sH[g * 104 + tig * 24 + c * 4] = u;
    }
    __syncthreads();

    const int w = t >> 6, l = t & 63;
    const int lm = l & 15, lq = l >> 4;
    const ushort_t* hp = &sH[(w * 16 + lm) * 104 + lq * 8];

    f32x4 acc[12];
    const f32x4 zf = {0.f, 0.f, 0.f, 0.f};
    #pragma unroll
    for (int mt = 0; mt < 12; ++mt) acc[mt] = zf;

    #pragma unroll
    for (int kk = 0; kk < 3; ++kk) {
        const short8 hb = *(const short8*)(hp + kk * 32);
        #pragma unroll
        for (int mt = 0; mt < 12; ++mt) {
            const short8 wa = *(const short8*)(g_Wit + (mt * 16 + lm) * 96 + kk * 32 + lq * 8);
            acc[mt] = __builtin_amdgcn_mfma_f32_16x16x32_bf16(wa, hb, acc[mt], 0, 0, 0);
        }
    }

    #pragma unroll
    for (int mt = 0; mt < 12; ++mt) {
        const int oc0 = mt * 16 + lq * 4;
        const float4 bv = *(const float4*)(b_in + oc0);
        uint2 u;
        u.x = (unsigned)f2bf(acc[mt][0] + bv.x) | ((unsigned)f2bf(acc[mt][1] + bv.y) << 16);
        u.y = (unsigned)f2bf(acc[mt][2] + bv.z) | ((unsigned)f2bf(acc[mt][3] + bv.w) << 16);
        *(uint2*)&sO[(w * 16 + lm) * 200 + oc0] = u;
    }
    __syncthreads();

    const char* sOb = (const char*)sO + w * 16 * 400;
    char* gdst = (char*)X1 + (size_t)(blockIdx.x * 64 + w * 16) * 384;
    #pragma unroll
    for (int c = 0; c < 6; ++c) {
        const int gb = c * 1024 + l * 16;
        const int px = gb / 384, b = gb - px * 384;
        const uint4 val = *(const uint4*)(sOb + px * 400 + b);
        *(uint4*)(gdst + gb) = val;
    }
}

// ---------------------------------------------------------------------------
// Kernel 2: 3x3 conv (192 -> 96) MFMA + bias + SiLU + residual.
// ROUND-16: deconfounded TLP test. r15 showed occupancy is GRID-limited
// (392 blocks = 1.53/CU; LDS and VGPR were never binding). r10's 128-px
// attempt was confounded by the (256,4) 64-VGPR spill clamp (WRITE 304 MB).
// Now: 128 px/block (wave = 32 px, acc[2][6] = 48 VGPR), grid 784 = 3.06
// blocks/CU (~12 waves/CU), single-buffered 36,864-B slab, (256,2) bounds
// -> no spill. Same staging reg-prefetch, XOR involution, race-fix barrier,
// coalesced epilogue. Bijective XCD swizzle: 784 = 8 * 98.
// ---------------------------------------------------------------------------
__global__ __launch_bounds__(256, 2) void k2_conv_mfma(
    const ushort_t* __restrict__ X1, const float* __restrict__ conv_b,
    const float* __restrict__ X, float* __restrict__ OUT)
{
    __shared__ ushort_t sW[TAPS];   // 36,864 B single buffer
    const int t = threadIdx.x;
    const int w = t >> 6, l = t & 63;
    const int lm = l & 15, lq = l >> 4;

    const int lb = ((int)blockIdx.x & 7) * K2_CPX + ((int)blockIdx.x >> 3);
    const int P0 = lb * 128 + w * 32;        // wave = 32 px; 32 | 3136
    const int img = P0 / 3136;
    const int ploc0 = P0 - img * 3136;
    int rr[2], cc[2];
    #pragma unroll
    for (int i = 0; i < 2; ++i) {
        const int pl = ploc0 + i * 16 + lm;
        rr[i] = pl / 56;
        cc[i] = pl - rr[i] * 56;
    }
    const size_t imgbase = (size_t)img * 3136 * 192;
    const int sbase = w * 9216 + l * 16;     // block covers whole 36,864-B slab

    f32x4 acc[2][6];
    const f32x4 zf = {0.f, 0.f, 0.f, 0.f};
    #pragma unroll
    for (int i = 0; i < 2; ++i)
        #pragma unroll
        for (int n = 0; n < 6; ++n) acc[i][n] = zf;

    const short8 zero8 = {0, 0, 0, 0, 0, 0, 0, 0};
    const int bkey = (lm & 7) << 4;
    const int bbase0 = lm * 384 + lq * 16;

    // ---- prologue: stage tap 0 ----
    uint4 r[9];
    #pragma unroll
    for (int j = 0; j < 9; ++j)
        r[j] = *(const uint4*)((const char*)g_Wt + sbase + j * 1024);
    #pragma unroll
    for (int j = 0; j < 9; ++j) {
        const int D = sbase + j * 1024;
        *(uint4*)((char*)sW + (D ^ (((D / 384) & 7) << 4))) = r[j];
    }
    __syncthreads();

    #pragma unroll 1
    for (int tap = 0; tap < 9; ++tap) {
        // prefetch next tap's slab into registers (hidden under MFMA phase)
        if (tap < 8) {
            const char* gsrc = (const char*)g_Wt + (size_t)(tap + 1) * TAPBYTES;
            #pragma unroll
            for (int j = 0; j < 9; ++j)
                r[j] = *(const uint4*)(gsrc + sbase + j * 1024);
        }

        const int ky = tap / 3, kx = tap - (tap / 3) * 3;
        const ushort_t* abase[2];
        bool av[2];
        #pragma unroll
        for (int i = 0; i < 2; ++i) {
            const int gr = rr[i] + ky - 1, gc = cc[i] + kx - 1;
            av[i] = (gr >= 0) && (gr < HH) && (gc >= 0) && (gc < WW);
            abase[i] = X1 + imgbase + (size_t)(gr * WW + gc) * 192 + lq * 8;
        }

        #pragma unroll
        for (int kk = 0; kk < 6; ++kk) {
            short8 b[6];
            #pragma unroll
            for (int n = 0; n < 6; ++n) {
                const int A = bbase0 + n * 6144 + kk * 64;
                b[n] = *(const short8*)((const char*)sW + (A ^ bkey));
            }
            short8 a[2];
            #pragma unroll
            for (int i = 0; i < 2; ++i)
                a[i] = av[i] ? *(const short8*)(abase[i] + kk * 32) : zero8;
            #pragma unroll
            for (int i = 0; i < 2; ++i)
                #pragma unroll
                for (int n = 0; n < 6; ++n)
                    acc[i][n] = __builtin_amdgcn_mfma_f32_16x16x32_bf16(
                        a[i], b[n], acc[i][n], 0, 0, 0);
        }
        __syncthreads();                     // all waves done reading sW

        if (tap < 8) {
            #pragma unroll
            for (int j = 0; j < 9; ++j) {
                const int D = sbase + j * 1024;
                *(uint4*)((char*)sW + (D ^ (((D / 384) & 7) << 4))) = r[j];
            }
            __syncthreads();                 // slab ready for next tap
        }
    }

    // ---- coalesced epilogue through LDS (sW now dead; barrier above) ----
    float* sY = (float*)sW + w * 1600;
    float bvn[6];
    #pragma unroll
    for (int n = 0; n < 6; ++n) bvn[n] = conv_b[n * 16 + lm];

    #pragma unroll
    for (int i = 0; i < 2; ++i) {            // fully unrolled: acc stays in VGPRs
        #pragma unroll
        for (int n = 0; n < 6; ++n) {
            #pragma unroll
            for (int r4 = 0; r4 < 4; ++r4) {
                const float y = acc[i][n][r4] + bvn[n];
                const float sig = 1.f / (1.f + __expf(-y));
                sY[(lq * 4 + r4) * 100 + n * 16 + lm] = y * sig;
            }
        }
        __syncthreads();
        const float* gx = X + (size_t)(P0 + i * 16) * 96;
        float* go = OUT + (size_t)(P0 + i * 16) * 96;
        #pragma unroll
        for (int c = 0; c < 6; ++c) {
            const int d = c * 256 + l * 4;
            const int px = d / 96, b = d - px * 96;
            const f32x4 yv = *(const f32x4*)(sY + px * 100 + b);
            const float4 xv = *(const float4*)(gx + d);
            float4 o;
            o.x = xv.x + yv[0]; o.y = xv.y + yv[1];
            o.z = xv.z + yv[2]; o.w = xv.w + yv[3];
            *(float4*)(go + d) = o;
        }
        __syncthreads();
    }
}

extern "C" void kernel_launch(void* const* d_in, const int* in_sizes, int n_in,
                              void* d_out, int out_size, void* d_ws, size_t ws_size,
                              hipStream_t stream) {
    (void)in_sizes; (void)n_in; (void)out_size; (void)ws_size;
    const float* X    = (const float*)d_in[0];
    const float* ln_w = (const float*)d_in[1];
    const float* ln_b = (const float*)d_in[2];
    const float* Wi   = (const float*)d_in[3];
    const float* b_in = (const float*)d_in[4];
    const float* Wc   = (const float*)d_in[5];
    const float* cb   = (const float*)d_in[6];
    float* OUT = (float*)d_out;
    ushort_t* X1 = (ushort_t*)d_ws;   // 100352*192 bf16 = 38.5 MB

    k0_wt<<<(9 * 96 * 192 + 255) / 256, 256, 0, stream>>>(Wc, Wi);
    k1_ln_proj<<<NPIX / 64, 256, 0, stream>>>(X, ln_w, ln_b, b_in, X1);
    k2_conv_mfma<<<K2_NWG, 256, 0, stream>>>(X1, cb, X, OUT);
}

// Round 17
// 135.887 us; speedup vs baseline: 1.4144x; 1.4144x over previous
//
#include <hip/hip_runtime.h>
#include <hip/hip_bf16.h>

#define D_MODEL 96
#define D_INNER 192
#define BATCH 32
#define HH 56
#define WW 56
#define NPIX (BATCH*HH*WW)   // 100352
#define LN_EPS 1e-5f
#define TAPS 18432           // shorts per tap slab (96 oc * 192 ic)
#define TAPBYTES 36864
#define K2_NWG 392           // NPIX / 256 = 8 * 49 (bijective XCD swizzle)
#define K2_CPX 49

typedef unsigned short ushort_t;
typedef __attribute__((ext_vector_type(8))) short short8;   // 8 bf16 (4 VGPRs)
typedef __attribute__((ext_vector_type(4))) float f32x4;

// g_Wt: conv weights [tap][oc][ic] bf16, PRE-SWIZZLED within each 36,864-B
// slab by the involution b -> b ^ (((b/384)&7)<<4) (byte units). k2 then
// copies each slab to LDS with fully-LINEAR global_load_lds (source linear,
// dest linear -- the m97-verified pattern) and the r15 XOR-swizzled B-reads
// recover logical data: LDS[A^key] = logical[A^key^key(row)] = logical[A].
// g_Wit: in_proj live-half [oc=192][ic=96] bf16 (unswizzled).
__device__ __align__(16) ushort_t g_Wt[9 * 96 * 192];
__device__ __align__(16) ushort_t g_Wit[192 * 96];

static __device__ __forceinline__ unsigned short f2bf(float f) {
    unsigned u = __float_as_uint(f);
    unsigned r = (u + 0x7fffu + ((u >> 16) & 1u)) >> 16;
    return (unsigned short)r;
}

// ---------------------------------------------------------------------------
// Kernel 0: weight prep. g_Wt stored PRE-SWIZZLED (short units: position s
// holds logical element s ^ (((s/192)&7)<<3); involution, row-preserving).
// ---------------------------------------------------------------------------
__global__ __launch_bounds__(256) void k0_wt(const float* __restrict__ Wc,
                                             const float* __restrict__ Wi) {
    const int o = blockIdx.x * 256 + threadIdx.x;
    if (o < 9 * 18432) {
        const int tap = o / 18432;
        const int s = o - tap * 18432;
        const int sl = s ^ (((s / 192) & 7) << 3);   // logical short index
        const int oc = sl / 192, ic = sl - oc * 192;
        g_Wt[o] = f2bf(Wc[(tap * 192 + ic) * 96 + oc]);
    }
    if (o < 192 * 96) {
        const int oc = o / 96, ic = o - oc * 96;
        g_Wit[o] = f2bf(Wi[ic * 384 + oc]);
    }
}

// ---------------------------------------------------------------------------
// Kernel 1: LayerNorm + in_projection. (byte-identical to round 9/11/15)
// ---------------------------------------------------------------------------
__global__ __launch_bounds__(256) void k1_ln_proj(
    const float* __restrict__ X, const float* __restrict__ ln_w,
    const float* __restrict__ ln_b, const float* __restrict__ b_in,
    ushort_t* __restrict__ X1)
{
    __shared__ ushort_t sH[64 * 104];
    __shared__ ushort_t sO[64 * 200];
    const int t = threadIdx.x;

    const int g = t >> 2, tig = t & 3;
    const int pix = blockIdx.x * 64 + g;
    const float* xp = X + (size_t)pix * 96 + tig * 24;
    float4 xq[6];
    float s = 0.f;
    #pragma unroll
    for (int c = 0; c < 6; ++c) {
        xq[c] = *(const float4*)(xp + c * 4);
        s += xq[c].x + xq[c].y + xq[c].z + xq[c].w;
    }
    s += __shfl_xor(s, 1, 4);
    s += __shfl_xor(s, 2, 4);
    const float mu = s * (1.f / 96.f);
    float v = 0.f;
    #pragma unroll
    for (int c = 0; c < 6; ++c) {
        const float d0 = xq[c].x - mu, d1 = xq[c].y - mu;
        const float d2 = xq[c].z - mu, d3 = xq[c].w - mu;
        v += d0 * d0 + d1 * d1 + d2 * d2 + d3 * d3;
    }
    v += __shfl_xor(v, 1, 4);
    v += __shfl_xor(v, 2, 4);
    const float rs = rsqrtf(v * (1.f / 96.f) + LN_EPS);
    #pragma unroll
    for (int c = 0; c < 6; ++c) {
        const float4 lw = *(const float4*)(ln_w + tig * 24 + c * 4);
        const float4 lb = *(const float4*)(ln_b + tig * 24 + c * 4);
        const unsigned p0 = (unsigned)f2bf((xq[c].x - mu) * rs * lw.x + lb.x)
                          | ((unsigned)f2bf((xq[c].y - mu) * rs * lw.y + lb.y) << 16);
        const unsigned p1 = (unsigned)f2bf((xq[c].z - mu) * rs * lw.z + lb.z)
                          | ((unsigned)f2bf((xq[c].w - mu) * rs * lw.w + lb.w) << 16);
        uint2 u; u.x = p0; u.y = p1;
        *(uint2*)&sH[g * 104 + tig * 24 + c * 4] = u;
    }
    __syncthreads();

    const int w = t >> 6, l = t & 63;
    const int lm = l & 15, lq = l >> 4;
    const ushort_t* hp = &sH[(w * 16 + lm) * 104 + lq * 8];

    f32x4 acc[12];
    const f32x4 zf = {0.f, 0.f, 0.f, 0.f};
    #pragma unroll
    for (int mt = 0; mt < 12; ++mt) acc[mt] = zf;

    #pragma unroll
    for (int kk = 0; kk < 3; ++kk) {
        const short8 hb = *(const short8*)(hp + kk * 32);
        #pragma unroll
        for (int mt = 0; mt < 12; ++mt) {
            const short8 wa = *(const short8*)(g_Wit + (mt * 16 + lm) * 96 + kk * 32 + lq * 8);
            acc[mt] = __builtin_amdgcn_mfma_f32_16x16x32_bf16(wa, hb, acc[mt], 0, 0, 0);
        }
    }

    #pragma unroll
    for (int mt = 0; mt < 12; ++mt) {
        const int oc0 = mt * 16 + lq * 4;
        const float4 bv = *(const float4*)(b_in + oc0);
        uint2 u;
        u.x = (unsigned)f2bf(acc[mt][0] + bv.x) | ((unsigned)f2bf(acc[mt][1] + bv.y) << 16);
        u.y = (unsigned)f2bf(acc[mt][2] + bv.z) | ((unsigned)f2bf(acc[mt][3] + bv.w) << 16);
        *(uint2*)&sO[(w * 16 + lm) * 200 + oc0] = u;
    }
    __syncthreads();

    const char* sOb = (const char*)sO + w * 16 * 400;
    char* gdst = (char*)X1 + (size_t)(blockIdx.x * 64 + w * 16) * 384;
    #pragma unroll
    for (int c = 0; c < 6; ++c) {
        const int gb = c * 1024 + l * 16;
        const int px = gb / 384, b = gb - px * 384;
        const uint4 val = *(const uint4*)(sOb + px * 400 + b);
        *(uint4*)(gdst + gb) = val;
    }
}

// ---------------------------------------------------------------------------
// Kernel 2: 3x3 conv (192 -> 96) MFMA + bias + SiLU + residual.
// ROUND-17: attack the measured (r13) additive A+W latency IN-WAVE.
//  (a) W-path: pre-swizzled g_Wt + fully-linear async global_load_lds into a
//      double-buffered slab (9 calls/tap, zero VGPRs, copies overlap MFMA;
//      the per-tap __syncthreads' vmcnt(0) drain is the only sync).
//  (b) A-path: batch ALL 24 A-fragment loads of the tap into a[4][6] regs
//      (24-deep MLP -> one latency bubble/tap instead of six), affordable
//      because (a) freed the 36 staging VGPRs.
// Everything else = r15: 256 px/block, grid 392 XCD-swizzled, (256,2),
// XOR-swizzled B-reads, race-fix barrier, coalesced epilogue.
// ---------------------------------------------------------------------------
__global__ __launch_bounds__(256, 2) void k2_conv_mfma(
    const ushort_t* __restrict__ X1, const float* __restrict__ conv_b,
    const float* __restrict__ X, float* __restrict__ OUT)
{
    __shared__ ushort_t sW[2][TAPS];   // 73,728 B double buffer
    const int t = threadIdx.x;
    const int w = t >> 6, l = t & 63;
    const int lm = l & 15, lq = l >> 4;

    const int lb = ((int)blockIdx.x & 7) * K2_CPX + ((int)blockIdx.x >> 3);
    const int P0 = lb * 256 + w * 64;
    const int img = P0 / 3136;
    const int ploc0 = P0 - img * 3136;
    int rr[4], cc[4];
    #pragma unroll
    for (int i = 0; i < 4; ++i) {
        const int pl = ploc0 + i * 16 + lm;
        rr[i] = pl / 56;
        cc[i] = pl - rr[i] * 56;
    }
    const size_t imgbase = (size_t)img * 3136 * 192;

    f32x4 acc[4][6];
    const f32x4 zf = {0.f, 0.f, 0.f, 0.f};
    #pragma unroll
    for (int i = 0; i < 4; ++i)
        #pragma unroll
        for (int n = 0; n < 6; ++n) acc[i][n] = zf;

    const short8 zero8 = {0, 0, 0, 0, 0, 0, 0, 0};
    const int bkey = (lm & 7) << 4;
    const int bbase0 = lm * 384 + lq * 16;

    // fully-linear async stage of one 36,864-B slab (9 x 4-KB block calls)
    auto stage = [&](int buf, int tap) {
        const char* g = (const char*)g_Wt + (size_t)tap * TAPBYTES + t * 16;
        char* d = (char*)&sW[buf][0] + t * 16;
        #pragma unroll
        for (int j = 0; j < 9; ++j)
            __builtin_amdgcn_global_load_lds(
                (const __attribute__((address_space(1))) unsigned*)(g + j * 4096),
                (__attribute__((address_space(3))) unsigned*)(d + j * 4096),
                16, 0, 0);
    };

    // ---- prologue: stage tap 0 into buf 0 ----
    stage(0, 0);
    __syncthreads();   // vmcnt(0) drain completes the copy

    #pragma unroll 1
    for (int tap = 0; tap < 9; ++tap) {
        if (tap < 8) stage((tap + 1) & 1, tap + 1);   // async, overlaps MFMA

        const int ky = tap / 3, kx = tap - (tap / 3) * 3;
        const ushort_t* abase[4];
        bool av[4];
        #pragma unroll
        for (int i = 0; i < 4; ++i) {
            const int gr = rr[i] + ky - 1, gc = cc[i] + kx - 1;
            av[i] = (gr >= 0) && (gr < HH) && (gc >= 0) && (gc < WW);
            abase[i] = X1 + imgbase + (size_t)(gr * WW + gc) * 192 + lq * 8;
        }

        // ---- batch ALL A-fragment loads for this tap (24-deep MLP) ----
        short8 a[4][6];
        #pragma unroll
        for (int kk = 0; kk < 6; ++kk)
            #pragma unroll
            for (int i = 0; i < 4; ++i)
                a[i][kk] = av[i] ? *(const short8*)(abase[i] + kk * 32) : zero8;

        const char* bufp = (const char*)&sW[tap & 1][0];
        #pragma unroll
        for (int kk = 0; kk < 6; ++kk) {
            short8 b[6];
            #pragma unroll
            for (int n = 0; n < 6; ++n) {
                const int A = bbase0 + n * 6144 + kk * 64;
                b[n] = *(const short8*)(bufp + (A ^ bkey));
            }
            #pragma unroll
            for (int i = 0; i < 4; ++i)
                #pragma unroll
                for (int n = 0; n < 6; ++n)
                    acc[i][n] = __builtin_amdgcn_mfma_f32_16x16x32_bf16(
                        a[i][kk], b[n], acc[i][n], 0, 0, 0);
        }
        __syncthreads();   // drains copies (vmcnt) + orders buffer reuse
    }

    // ---- coalesced epilogue through LDS (sW now dead; barrier above) ----
    float* sY = (float*)&sW[0][0] + w * 1600;
    float bvn[6];
    #pragma unroll
    for (int n = 0; n < 6; ++n) bvn[n] = conv_b[n * 16 + lm];

    #pragma unroll
    for (int i = 0; i < 4; ++i) {           // fully unrolled: acc stays in VGPRs
        #pragma unroll
        for (int n = 0; n < 6; ++n) {
            #pragma unroll
            for (int r4 = 0; r4 < 4; ++r4) {
                const float y = acc[i][n][r4] + bvn[n];
                const float sig = 1.f / (1.f + __expf(-y));
                sY[(lq * 4 + r4) * 100 + n * 16 + lm] = y * sig;
            }
        }
        __syncthreads();
        const float* gx = X + (size_t)(P0 + i * 16) * 96;
        float* go = OUT + (size_t)(P0 + i * 16) * 96;
        #pragma unroll
        for (int c = 0; c < 6; ++c) {
            const int d = c * 256 + l * 4;
            const int px = d / 96, b = d - px * 96;
            const f32x4 yv = *(const f32x4*)(sY + px * 100 + b);
            const float4 xv = *(const float4*)(gx + d);
            float4 o;
            o.x = xv.x + yv[0]; o.y = xv.y + yv[1];
            o.z = xv.z + yv[2]; o.w = xv.w + yv[3];
            *(float4*)(go + d) = o;
        }
        __syncthreads();
    }
}

extern "C" void kernel_launch(void* const* d_in, const int* in_sizes, int n_in,
                              void* d_out, int out_size, void* d_ws, size_t ws_size,
                              hipStream_t stream) {
    (void)in_sizes; (void)n_in; (void)out_size; (void)ws_size;
    const float* X    = (const float*)d_in[0];
    const float* ln_w = (const float*)d_in[1];
    const float* ln_b = (const float*)d_in[2];
    const float* Wi   = (const float*)d_in[3];
    const float* b_in = (const float*)d_in[4];
    const float* Wc   = (const float*)d_in[5];
    const float* cb   = (const float*)d_in[6];
    float* OUT = (float*)d_out;
    ushort_t* X1 = (ushort_t*)d_ws;   // 100352*192 bf16 = 38.5 MB

    k0_wt<<<(9 * 96 * 192 + 255) / 256, 256, 0, stream>>>(Wc, Wi);
    k1_ln_proj<<<NPIX / 64, 256, 0, stream>>>(X, ln_w, ln_b, b_in, X1);
    k2_conv_mfma<<<K2_NWG, 256, 0, stream>>>(X1, cb, X, OUT);
}

// Round 21
// 130.625 us; speedup vs baseline: 1.4714x; 1.0403x over previous
//
#include <hip/hip_runtime.h>
#include <hip/hip_bf16.h>

#define D_MODEL 96
#define D_INNER 192
#define BATCH 32
#define HH 56
#define WW 56
#define NPIX (BATCH*HH*WW)   // 100352
#define LN_EPS 1e-5f
#define TAPS 18432           // shorts per tap slab (96 oc * 192 ic)
#define TAPBYTES 36864
#define K2_NWG 1568          // NPIX / 64 = 8 * 196 (bijective XCD swizzle)
#define K2_CPX 196

typedef unsigned short ushort_t;
typedef __attribute__((ext_vector_type(8))) short short8;   // 8 bf16 (4 VGPRs)
typedef __attribute__((ext_vector_type(4))) float f32x4;

// g_Wt: conv weights [tap][oc][ic] bf16, PRE-SWIZZLED within each slab by
// byte ^= ((byte/384 &7)<<4) (r17-verified). g_Wit: in_proj [oc][ic] bf16.
__device__ __align__(16) ushort_t g_Wt[9 * 96 * 192];
__device__ __align__(16) ushort_t g_Wit[192 * 96];

static __device__ __forceinline__ unsigned short f2bf(float f) {
    unsigned u = __float_as_uint(f);
    unsigned r = (u + 0x7fffu + ((u >> 16) & 1u)) >> 16;
    return (unsigned short)r;
}

// ---------------------------------------------------------------------------
// Kernel 0: weight prep (byte-identical to r17, verified).
// ---------------------------------------------------------------------------
__global__ __launch_bounds__(256) void k0_wt(const float* __restrict__ Wc,
                                             const float* __restrict__ Wi) {
    const int o = blockIdx.x * 256 + threadIdx.x;
    if (o < 9 * 18432) {
        const int tap = o / 18432;
        const int s = o - tap * 18432;
        const int sl = s ^ (((s / 192) & 7) << 3);   // logical short index
        const int oc = sl / 192, ic = sl - oc * 192;
        g_Wt[o] = f2bf(Wc[(tap * 192 + ic) * 96 + oc]);
    }
    if (o < 192 * 96) {
        const int oc = o / 96, ic = o - oc * 96;
        g_Wit[o] = f2bf(Wi[ic * 384 + oc]);
    }
}

// ---------------------------------------------------------------------------
// Kernel 1: LayerNorm + in_projection (r9-verified math). ONE change: the
// X1 store is PRE-SWIZZLED per pixel: byte ^= ((pix&7)<<4). Valid because
// 56 % 8 == 0 -> pix&7 == image-column&7, so k2 can reconstruct the key.
// XOR acts on bits 4-6, inside the pixel's 384-B block (3 aligned 128-B
// windows), keeps 16-B alignment, keeps 128-B coalescing segments.
// ---------------------------------------------------------------------------
__global__ __launch_bounds__(256) void k1_ln_proj(
    const float* __restrict__ X, const float* __restrict__ ln_w,
    const float* __restrict__ ln_b, const float* __restrict__ b_in,
    ushort_t* __restrict__ X1)
{
    __shared__ ushort_t sH[64 * 104];
    __shared__ ushort_t sO[64 * 200];
    const int t = threadIdx.x;

    const int g = t >> 2, tig = t & 3;
    const int pix = blockIdx.x * 64 + g;
    const float* xp = X + (size_t)pix * 96 + tig * 24;
    float4 xq[6];
    float s = 0.f;
    #pragma unroll
    for (int c = 0; c < 6; ++c) {
        xq[c] = *(const float4*)(xp + c * 4);
        s += xq[c].x + xq[c].y + xq[c].z + xq[c].w;
    }
    s += __shfl_xor(s, 1, 4);
    s += __shfl_xor(s, 2, 4);
    const float mu = s * (1.f / 96.f);
    float v = 0.f;
    #pragma unroll
    for (int c = 0; c < 6; ++c) {
        const float d0 = xq[c].x - mu, d1 = xq[c].y - mu;
        const float d2 = xq[c].z - mu, d3 = xq[c].w - mu;
        v += d0 * d0 + d1 * d1 + d2 * d2 + d3 * d3;
    }
    v += __shfl_xor(v, 1, 4);
    v += __shfl_xor(v, 2, 4);
    const float rs = rsqrtf(v * (1.f / 96.f) + LN_EPS);
    #pragma unroll
    for (int c = 0; c < 6; ++c) {
        const float4 lw = *(const float4*)(ln_w + tig * 24 + c * 4);
        const float4 lb = *(const float4*)(ln_b + tig * 24 + c * 4);
        const unsigned p0 = (unsigned)f2bf((xq[c].x - mu) * rs * lw.x + lb.x)
                          | ((unsigned)f2bf((xq[c].y - mu) * rs * lw.y + lb.y) << 16);
        const unsigned p1 = (unsigned)f2bf((xq[c].z - mu) * rs * lw.z + lb.z)
                          | ((unsigned)f2bf((xq[c].w - mu) * rs * lw.w + lb.w) << 16);
        uint2 u; u.x = p0; u.y = p1;
        *(uint2*)&sH[g * 104 + tig * 24 + c * 4] = u;
    }
    __syncthreads();

    const int w = t >> 6, l = t & 63;
    const int lm = l & 15, lq = l >> 4;
    const ushort_t* hp = &sH[(w * 16 + lm) * 104 + lq * 8];

    f32x4 acc[12];
    const f32x4 zf = {0.f, 0.f, 0.f, 0.f};
    #pragma unroll
    for (int mt = 0; mt < 12; ++mt) acc[mt] = zf;

    #pragma unroll
    for (int kk = 0; kk < 3; ++kk) {
        const short8 hb = *(const short8*)(hp + kk * 32);
        #pragma unroll
        for (int mt = 0; mt < 12; ++mt) {
            const short8 wa = *(const short8*)(g_Wit + (mt * 16 + lm) * 96 + kk * 32 + lq * 8);
            acc[mt] = __builtin_amdgcn_mfma_f32_16x16x32_bf16(wa, hb, acc[mt], 0, 0, 0);
        }
    }

    #pragma unroll
    for (int mt = 0; mt < 12; ++mt) {
        const int oc0 = mt * 16 + lq * 4;
        const float4 bv = *(const float4*)(b_in + oc0);
        uint2 u;
        u.x = (unsigned)f2bf(acc[mt][0] + bv.x) | ((unsigned)f2bf(acc[mt][1] + bv.y) << 16);
        u.y = (unsigned)f2bf(acc[mt][2] + bv.z) | ((unsigned)f2bf(acc[mt][3] + bv.w) << 16);
        *(uint2*)&sO[(w * 16 + lm) * 200 + oc0] = u;
    }
    __syncthreads();

    const char* sOb = (const char*)sO + w * 16 * 400;
    char* gdst = (char*)X1 + (size_t)(blockIdx.x * 64 + w * 16) * 384;
    #pragma unroll
    for (int c = 0; c < 6; ++c) {
        const int gb = c * 1024 + l * 16;
        const int px = gb / 384, b = gb - px * 384;
        const uint4 val = *(const uint4*)(sOb + px * 400 + b);
        // pre-swizzled store: bits 4-6 of the in-block offset XOR'd by px&7
        *(uint4*)(gdst + (gb ^ ((px & 7) << 4))) = val;
    }
}

// ---------------------------------------------------------------------------
// Kernel 2: 3x3 conv (192 -> 96) MFMA + bias + SiLU + residual.
// ROUND-18 (third resubmit): halo-in-LDS, conflict-free. Block = 128 thr
// (2 waves), one 8x8 output tile; halo 10x10x192 bf16 staged VERBATIM (X1
// pre-swizzled by k1 -> A-reads XOR ((gcol&7)<<4); bank algebra = b128
// floor). Zero borders pre-filled -> no branches in the main loop.
// Weights: r17's pre-swizzled g_Wt + linear global_load_lds, single slab.
// LDS 75,264 B -> 2 blocks/CU. Wave = 64 px x 48 oc (acc[4][3]).
// Main loop: ZERO global accesses.
// ---------------------------------------------------------------------------
__global__ __launch_bounds__(128) void k2_conv_mfma(
    const ushort_t* __restrict__ X1, const float* __restrict__ conv_b,
    const float* __restrict__ X, float* __restrict__ OUT)
{
    __shared__ ushort_t sX[100 * 192];   // 38,400 B halo (pre-swizzled blocks)
    __shared__ ushort_t sWs[TAPS];       // 36,864 B tap slab (pre-swizzled)
    const int t = threadIdx.x;
    const int w = t >> 6, l = t & 63;
    const int lm = l & 15, lq = l >> 4;

    const int lb = ((int)blockIdx.x & 7) * K2_CPX + ((int)blockIdx.x >> 3);
    const int img = lb / 49, tile = lb - img * 49;
    const int ty = (tile / 7) * 8, tx = (tile % 7) * 8;
    const size_t imgbase = (size_t)img * 3136 * 192;

    // ---- stage halo: verbatim copies (swizzle travels with the data) ----
    for (int idx = t; idx < 2400; idx += 128) {       // 100 px * 24 uint4
        const int hp2 = idx / 24, q = idx - hp2 * 24;
        const int hr = hp2 / 10, hc = hp2 - hr * 10;
        const int gr = ty + hr - 1, gc = tx + hc - 1;
        uint4 val = make_uint4(0u, 0u, 0u, 0u);
        if (gr >= 0 && gr < HH && gc >= 0 && gc < WW)
            val = *(const uint4*)(X1 + imgbase + (size_t)(gr * WW + gc) * 192 + q * 8);
        *(uint4*)&sX[hp2 * 192 + q * 8] = val;
    }

    // ---- W staging: linear async copy (src and dest both linear) ----
    auto stageW = [&](int tap) {
        const char* g = (const char*)g_Wt + (size_t)tap * TAPBYTES + t * 16;
        char* d = (char*)sWs + t * 16;
        #pragma unroll
        for (int j = 0; j < 18; ++j)
            __builtin_amdgcn_global_load_lds(
                (const __attribute__((address_space(1))) unsigned*)(g + j * 2048),
                (__attribute__((address_space(3))) unsigned*)(d + j * 2048),
                16, 0, 0);
    };
    stageW(0);
    __syncthreads();   // halo written + tap-0 slab drained

    int pr[4], pc[4];
    #pragma unroll
    for (int i = 0; i < 4; ++i) {
        const int px = i * 16 + lm;
        pr[i] = px >> 3; pc[i] = px & 7;
    }

    f32x4 acc[4][3];
    const f32x4 zf = {0.f, 0.f, 0.f, 0.f};
    #pragma unroll
    for (int i = 0; i < 4; ++i)
        #pragma unroll
        for (int n = 0; n < 3; ++n) acc[i][n] = zf;

    const int bkey = (lm & 7) << 4;
    const int brow0 = (w * 48 + lm) * 384 + lq * 16;   // wave's oc base row

    #pragma unroll 1
    for (int tap = 0; tap < 9; ++tap) {
        const int ky = tap / 3, kx = tap - (tap / 3) * 3;
        int abyte[4], akey[4];
        #pragma unroll
        for (int i = 0; i < 4; ++i) {
            abyte[i] = ((pr[i] + ky) * 10 + pc[i] + kx) * 384;
            akey[i] = ((tx + pc[i] + kx - 1) & 7) << 4;   // zeros if border
        }

        #pragma unroll
        for (int kk = 0; kk < 6; ++kk) {
            short8 b[3];
            #pragma unroll
            for (int n = 0; n < 3; ++n) {
                const int A = brow0 + n * 6144 + kk * 64;
                b[n] = *(const short8*)((const char*)sWs + (A ^ bkey));
            }
            short8 a[4];
            #pragma unroll
            for (int i = 0; i < 4; ++i) {
                const int s = (kk * 64 + lq * 16) ^ akey[i];
                a[i] = *(const short8*)((const char*)sX + abyte[i] + s);
            }
            #pragma unroll
            for (int i = 0; i < 4; ++i)
                #pragma unroll
                for (int n = 0; n < 3; ++n)
                    acc[i][n] = __builtin_amdgcn_mfma_f32_16x16x32_bf16(
                        a[i], b[n], acc[i][n], 0, 0, 0);
        }
        __syncthreads();                 // all waves done reading sWs (+sX last tap)
        if (tap < 8) { stageW(tap + 1); __syncthreads(); }
    }

    // ---- epilogue: silu via LDS transpose (sX dead), coalesced stores ----
    float* sY = (float*)sX;              // 64 px * 100 dw = 25,600 B
    float bvn[3];
    #pragma unroll
    for (int n = 0; n < 3; ++n) bvn[n] = conv_b[w * 48 + n * 16 + lm];

    #pragma unroll
    for (int i = 0; i < 4; ++i)
        #pragma unroll
        for (int n = 0; n < 3; ++n)
            #pragma unroll
            for (int r4 = 0; r4 < 4; ++r4) {
                const float y = acc[i][n][r4] + bvn[n];
                const float sig = 1.f / (1.f + __expf(-y));
                sY[(i * 16 + lq * 4 + r4) * 100 + w * 48 + n * 16 + lm] = y * sig;
            }
    __syncthreads();

    #pragma unroll
    for (int c = 0; c < 12; ++c) {
        const int d = c * 512 + t * 4;                 // < 6144
        const int px = d / 96, b = d - px * 96;
        const int grow = ty + (px >> 3), gcol = tx + (px & 7);
        const size_t gdw = ((size_t)img * 3136 + grow * 56 + gcol) * 96 + b;
        const f32x4 yv = *(const f32x4*)(sY + px * 100 + b);
        const float4 xv = *(const float4*)(X + gdw);
        float4 o;
        o.x = xv.x + yv[0]; o.y = xv.y + yv[1];
        o.z = xv.z + yv[2]; o.w = xv.w + yv[3];
        *(float4*)(OUT + gdw) = o;
    }
}

extern "C" void kernel_launch(void* const* d_in, const int* in_sizes, int n_in,
                              void* d_out, int out_size, void* d_ws, size_t ws_size,
                              hipStream_t stream) {
    (void)in_sizes; (void)n_in; (void)out_size; (void)ws_size;
    const float* X    = (const float*)d_in[0];
    const float* ln_w = (const float*)d_in[1];
    const float* ln_b = (const float*)d_in[2];
    const float* Wi   = (const float*)d_in[3];
    const float* b_in = (const float*)d_in[4];
    const float* Wc   = (const float*)d_in[5];
    const float* cb   = (const float*)d_in[6];
    float* OUT = (float*)d_out;
    ushort_t* X1 = (ushort_t*)d_ws;   // 100352*192 bf16 = 38.5 MB (pre-swizzled)

    k0_wt<<<(9 * 96 * 192 + 255) / 256, 256, 0, stream>>>(Wc, Wi);
    k1_ln_proj<<<NPIX / 64, 256, 0, stream>>>(X, ln_w, ln_b, b_in, X1);
    k2_conv_mfma<<<K2_NWG, 128, 0, stream>>>(X1, cb, X, OUT);
}